// Round 10
// baseline (345.444 us; speedup 1.0000x reference)
//
#include <hip/hip_runtime.h>
#include <math.h>

#define Bdim 32
#define Adim 256
#define Ndim 64
#define Gdim 50
#define Fdim 128

typedef __attribute__((ext_vector_type(8)))  short short8;
typedef __attribute__((ext_vector_type(16))) float floatx16;

// manual RNE f32->bf16 (inputs finite by construction)
__device__ __forceinline__ unsigned bfround(float x) {
    unsigned u = __builtin_bit_cast(unsigned, x);
    return u + 0x7FFFu + ((u >> 16) & 1u);   // rounded value in bits [31:16]
}
__device__ __forceinline__ unsigned short f2bf_u(float x) {
    return (unsigned short)(bfround(x) >> 16);
}
__device__ __forceinline__ unsigned pk2bf(float a, float b) {
    return (bfround(a) >> 16) | (bfround(b) & 0xFFFF0000u);
}
__device__ __forceinline__ float bf2f(unsigned short v) {
    return __builtin_bit_cast(float, ((unsigned)v) << 16);
}
// shifted softplus = ln(1+e^v) - ln2 = ln2*(log2(1+2^(v*log2e)) - 1)
// __builtin_exp2f/__builtin_log2f legalize to v_exp_f32 / v_log_f32 on amdgcn
__device__ __forceinline__ float sspf(float v) {
    float t = __builtin_exp2f(v * 1.44269504089f);
    return fmaf(__builtin_log2f(1.0f + t), 0.69314718056f, -0.69314718056f);
}
__device__ __forceinline__ short8 mk8(unsigned a, unsigned b, unsigned c, unsigned d) {
    union { unsigned u[4]; short8 s; } t;
    t.u[0] = a; t.u[1] = b; t.u[2] = c; t.u[3] = d;
    return t.s;
}

// ---------------------------------------------------------------------------
// Kernel 0: fw1t[f][g] = bf16(fw1[g][f]) for g<50, fb1[f] at g=50, 0 after.
// ---------------------------------------------------------------------------
__global__ __launch_bounds__(256) void prep_fw1t(const float* __restrict__ fw1,
                                                 const float* __restrict__ fb1,
                                                 unsigned short* __restrict__ fw1t) {
    int idx = blockIdx.x * 256 + threadIdx.x;   // = f*64 + g
    int f = idx >> 6, g = idx & 63;
    float v = (g < Gdim) ? fw1[g * Fdim + f] : ((g == Gdim) ? fb1[f] : 0.0f);
    fw1t[idx] = f2bf_u(v);
}

// ---------------------------------------------------------------------------
// Kernel 1: y = x @ in2f_w via bf16 MFMA, y in bf16.
// 256 blocks x 32 rows (full-machine). A-frags straight from global x;
// w^T staged once per block in LDS. Wave wv owns f-tile [32*wv, 32*wv+32).
// ---------------------------------------------------------------------------
__global__ __launch_bounds__(256) void in2f_v3(const float* __restrict__ x,
                                               const float* __restrict__ w,
                                               unsigned short* __restrict__ y) {
    __shared__ short sWT[128 * 132];   // w^T[f][i]  33792 B
    const int tid = threadIdx.x;
#pragma unroll 4
    for (int k = 0; k < 32; ++k) {
        int idx = tid + k * 256;             // float2 index, 8192 total
        float2 v = *(const float2*)(w + 2 * idx);
        int i = idx >> 6;                    // input channel (w row)
        int f = (2 * idx) & 127;
        sWT[f * 132 + i]       = (short)f2bf_u(v.x);
        sWT[(f + 1) * 132 + i] = (short)f2bf_u(v.y);
    }
    __syncthreads();

    const int wv = tid >> 6, lane = tid & 63, lm = lane & 31, lh = lane >> 5;
    const int rbase = blockIdx.x * 32;
    floatx16 acc;
#pragma unroll
    for (int e = 0; e < 16; ++e) acc[e] = 0.0f;

    const float* xr = x + (size_t)(rbase + lm) * Fdim;
#pragma unroll
    for (int ks = 0; ks < 8; ++ks) {
        int g0 = ks * 16 + lh * 8;
        float4 q0 = *(const float4*)(xr + g0);
        float4 q1 = *(const float4*)(xr + g0 + 4);
        short8 a = mk8(pk2bf(q0.x, q0.y), pk2bf(q0.z, q0.w),
                       pk2bf(q1.x, q1.y), pk2bf(q1.z, q1.w));
        const short* bp = &sWT[(wv * 32 + lm) * 132 + g0];
        uint2 b0 = *(const uint2*)bp;
        uint2 b1 = *(const uint2*)(bp + 4);
        acc = __builtin_amdgcn_mfma_f32_32x32x16_bf16(
            a, mk8(b0.x, b0.y, b1.x, b1.y), acc, 0, 0, 0);
    }
#pragma unroll
    for (int r = 0; r < 16; ++r) {
        int row = rbase + (r & 3) + 8 * (r >> 2) + 4 * lh;
        y[(size_t)row * Fdim + wv * 32 + lm] = f2bf_u(acc[r]);
    }
}

// ---------------------------------------------------------------------------
// Kernel 2: fused filter-net + cutoff + gather + neighbor reduction.
// Block = super-pair (2 sites, 128 rows); wave = 32 rows exclusive.
// dense1: A = fw1t (GLOBAL, L2-hot, dwordx4), B = f_ij (LDS, staged
// coalesced); W1 in registers (shfl remap); dense2: A = regs, B = fw2T (LDS).
// LDS = 33792 + 15424 + 512 + 512 + 2048 = 52288 B -> 3 blocks/CU, 12 waves.
// ---------------------------------------------------------------------------
#define SF2 132   // sFw2 stride (shorts)
#define SFI 60    // sFij stride (shorts)

__global__ __launch_bounds__(256, 3) void cfconv_v4(
    const float* __restrict__ r_ij, const float* __restrict__ f_ij,
    const float* __restrict__ mask, const int* __restrict__ nbr,
    const unsigned short* __restrict__ fw1t,
    const float* __restrict__ fw2, const float* __restrict__ fb2,
    const unsigned short* __restrict__ ybf, float* __restrict__ out)
{
    __shared__ short sFw2[128 * SF2];        // fw2T[f][h]
    __shared__ short sFij[128 * SFI + 16];   // [(site,n)][g] bf16 + tail pad
    __shared__ float sCm[128];
    __shared__ int   sNbr[128];
    __shared__ float sRed[4 * 128];

    const int tid = threadIdx.x, wv = tid >> 6, lane = tid & 63;
    const int lm = lane & 31, lh = lane >> 5;

    // ---- stage fw2T once per block ----
    for (int idx = tid; idx < Fdim * Fdim; idx += 256) {
        int h = idx >> 7, f = idx & 127;
        sFw2[f * SF2 + h] = (short)f2bf_u(fw2[idx]);
    }
    // sFij constant columns g=50..59 (bias 1.0 at g=50, zeros after) + pad
    for (int idx = tid; idx < 128 * 5; idx += 256) {
        int row = idx / 5, k = idx - row * 5;
        *(unsigned*)&sFij[row * SFI + 50 + 2 * k] = (k == 0) ? 0x00003F80u : 0u;
    }
    if (tid < 8) *(unsigned*)&sFij[128 * SFI + 2 * tid] = 0u;

    float fb2v[4];
#pragma unroll
    for (int jt = 0; jt < 4; ++jt) fb2v[jt] = fb2[jt * 32 + lm];

    for (int it = 0; it < 4; ++it) {
        const int sp = blockIdx.x + 1024 * it;

        // ---- stage f_ij tile: 2*64*50 = 6400 floats = 3200 float2 ----
        const float* fp = f_ij + (size_t)sp * (2 * Ndim * Gdim);
#pragma unroll
        for (int k = 0; k < 13; ++k) {
            int idx = tid + k * 256;
            if (idx < 3200) {
                float2 v = *(const float2*)(fp + 2 * idx);
                int row = idx / 25;
                int g   = 2 * idx - row * 50;
                *(unsigned*)&sFij[row * SFI + g] = pk2bf(v.x, v.y);
            }
        }
        if (tid < 128) {
            int site = sp * 2 + (tid >> 6), n = tid & 63;
            float r = r_ij[(size_t)site * Ndim + n];
            float c = 0.5f * (__cosf(r * 0.62831853071796f) + 1.0f);
            c = (r < 5.0f) ? c : 0.0f;
            sCm[tid]  = c * mask[(size_t)site * Ndim + n];
            sNbr[tid] = nbr[(size_t)site * Ndim + n];
        }
        __syncthreads();   // B1: staging done

        // ---- dense1 B-frags (f_ij rows) hoisted once from LDS ----
        const int rowb = wv * 32;
        unsigned bfr[4][4];
#pragma unroll
        for (int ks = 0; ks < 4; ++ks) {
            const short* bp = &sFij[(rowb + lm) * SFI + ks * 16 + lh * 8];
            uint2 b0 = *(const uint2*)bp;
            uint2 b1 = *(const uint2*)(bp + 4);
            bfr[ks][0] = b0.x; bfr[ks][1] = b0.y;
            bfr[ks][2] = b1.x; bfr[ks][3] = b1.y;
        }

        // ---- dense1: A = fw1t (global, L2), ssp, remap D -> dense2 A-frags ----
        unsigned A2[8][4];
#pragma unroll
        for (int ft = 0; ft < 4; ++ft) {
            floatx16 a1;
#pragma unroll
            for (int e = 0; e < 16; ++e) a1[e] = 0.0f;
#pragma unroll
            for (int ks = 0; ks < 4; ++ks) {
                uint4 av = *(const uint4*)(fw1t + (ft * 32 + lm) * 64 + ks * 16 + lh * 8);
                a1 = __builtin_amdgcn_mfma_f32_32x32x16_bf16(
                    mk8(av.x, av.y, av.z, av.w),
                    mk8(bfr[ks][0], bfr[ks][1], bfr[ks][2], bfr[ks][3]),
                    a1, 0, 0, 0);
            }
            unsigned P[8], X[8];
#pragma unroll
            for (int q = 0; q < 8; ++q)
                P[q] = pk2bf(sspf(a1[2 * q]), sspf(a1[2 * q + 1]));
#pragma unroll
            for (int q = 0; q < 8; ++q) X[q] = (unsigned)__shfl_xor((int)P[q], 32);
            A2[2*ft][0]   = lh ? X[2] : P[0];  A2[2*ft][1]   = lh ? X[3] : P[1];
            A2[2*ft][2]   = lh ? P[2] : X[0];  A2[2*ft][3]   = lh ? P[3] : X[1];
            A2[2*ft+1][0] = lh ? X[6] : P[4];  A2[2*ft+1][1] = lh ? X[7] : P[5];
            A2[2*ft+1][2] = lh ? P[6] : X[4];  A2[2*ft+1][3] = lh ? P[7] : X[5];
        }

        // ---- dense2: A = W1 (regs), B = fw2T (LDS) ----
        floatx16 acc2[4];
#pragma unroll
        for (int jt = 0; jt < 4; ++jt)
#pragma unroll
            for (int e = 0; e < 16; ++e) acc2[jt][e] = 0.0f;
#pragma unroll
        for (int ks = 0; ks < 8; ++ks) {
            short8 a = mk8(A2[ks][0], A2[ks][1], A2[ks][2], A2[ks][3]);
#pragma unroll
            for (int jt = 0; jt < 4; ++jt) {
                const short* bp = &sFw2[(jt * 32 + lm) * SF2 + ks * 16 + lh * 8];
                uint2 b0 = *(const uint2*)bp;
                uint2 b1 = *(const uint2*)(bp + 4);
                acc2[jt] = __builtin_amdgcn_mfma_f32_32x32x16_bf16(
                    a, mk8(b0.x, b0.y, b1.x, b1.y), acc2[jt], 0, 0, 0);
            }
        }

        // ---- epilogue: out[f] += cm[n]*(W2[n,f]+fb2[f])*y[nbr[n],f] ----
        const int ps = sp * 2 + (wv >> 1);
        float cmv[16]; int nbv[16];
#pragma unroll
        for (int rq = 0; rq < 4; ++rq) {
            float4 c4 = *(const float4*)&sCm[wv * 32 + rq * 8 + lh * 4];
            int4   n4 = *(const int4*)&sNbr[wv * 32 + rq * 8 + lh * 4];
            cmv[rq*4+0] = c4.x; cmv[rq*4+1] = c4.y; cmv[rq*4+2] = c4.z; cmv[rq*4+3] = c4.w;
            nbv[rq*4+0] = n4.x; nbv[rq*4+1] = n4.y; nbv[rq*4+2] = n4.z; nbv[rq*4+3] = n4.w;
        }
        const int bofs = (ps >> 8) * Adim;
        float part[4] = {0.f, 0.f, 0.f, 0.f};
#pragma unroll
        for (int r = 0; r < 16; ++r) {
            float cm = cmv[r];
            const unsigned short* yr = ybf + (size_t)(bofs + nbv[r]) * Fdim;
#pragma unroll
            for (int jt = 0; jt < 4; ++jt) {
                float yv = bf2f(yr[jt * 32 + lm]);
                part[jt] += (acc2[jt][r] + fb2v[jt]) * cm * yv;
            }
        }
#pragma unroll
        for (int jt = 0; jt < 4; ++jt) {
            float s = part[jt] + __shfl_xor(part[jt], 32);
            if (lh == 0) sRed[wv * 128 + jt * 32 + lm] = s;
        }
        __syncthreads();   // B2
        {
            int s = tid >> 7, f = tid & 127;
            out[(size_t)(sp * 2 + s) * Fdim + f] =
                sRed[(2 * s) * 128 + f] + sRed[(2 * s + 1) * 128 + f];
        }
    }
}

// ---------------------------------------------------------------------------
extern "C" void kernel_launch(void* const* d_in, const int* in_sizes, int n_in,
                              void* d_out, int out_size, void* d_ws, size_t ws_size,
                              hipStream_t stream) {
    const float* x      = (const float*)d_in[0];
    const float* r_ij   = (const float*)d_in[1];
    const float* f_ij   = (const float*)d_in[2];
    const float* mask   = (const float*)d_in[3];
    const int*   nbr    = (const int*)d_in[4];
    const float* in2f_w = (const float*)d_in[5];
    const float* fw1    = (const float*)d_in[6];
    const float* fb1    = (const float*)d_in[7];
    const float* fw2    = (const float*)d_in[8];
    const float* fb2    = (const float*)d_in[9];
    float* out = (float*)d_out;
    unsigned short* y    = (unsigned short*)d_ws;          // 2 MB bf16
    unsigned short* fw1t = y + (size_t)Bdim * Adim * Fdim; // 16 KB bf16

    prep_fw1t<<<32, 256, 0, stream>>>(fw1, fb1, fw1t);
    in2f_v3<<<256, 256, 0, stream>>>(x, in2f_w, y);
    cfconv_v4<<<1024, 256, 0, stream>>>(r_ij, f_ij, mask, nbr,
                                        fw1t, fw2, fb2, y, out);
}